// Round 5
// baseline (7353.387 us; speedup 1.0000x reference)
//
#include <hip/hip_runtime.h>

#define NN 200000     // nodes
#define NE 640000     // edges
#define HD 128        // hidden
#define NL 5          // layers
#define PHD 512       // proj hidden
#define NB 8000       // graphs
#define MAXV 119
#define SBLK 1024     // stats partial blocks

// ---------------- AtomEncoder: h[n,c] = sum_s emb[s, x[n,s], c] ----------------
__global__ __launch_bounds__(256) void k_encoder(const int* __restrict__ x,
    const float* __restrict__ emb, float* __restrict__ h) {
  int idx = blockIdx.x * 256 + threadIdx.x;
  if (idx >= NN * HD) return;
  int n = idx >> 7, c = idx & 127;
  const int* xr = x + n * 9;
  float acc = 0.f;
#pragma unroll
  for (int s = 0; s < 9; ++s)
    acc += emb[(s * MAXV + xr[s]) * HD + c];
  h[idx] = acc;
}

// ---------------- A = (1+eps[l]) * h ----------------
__global__ __launch_bounds__(256) void k_init_a(const float4* __restrict__ h4,
    const float* __restrict__ eps, int l, float4* __restrict__ A4) {
  int idx = blockIdx.x * 256 + threadIdx.x;
  if (idx >= NN * HD / 4) return;
  float e = 1.f + eps[l];
  float4 v = h4[idx];
  A4[idx] = make_float4(e * v.x, e * v.y, e * v.z, e * v.w);
}

// ---------------- A[dst] += h[src] over edges (atomic scatter) ----------------
__global__ __launch_bounds__(256) void k_scatter(const int* __restrict__ src,
    const int* __restrict__ dst, const float* __restrict__ h, float* __restrict__ A) {
  int idx = blockIdx.x * 256 + threadIdx.x;
  if (idx >= NE * 32) return;
  int e = idx >> 5, ch = idx & 31;
  int s = src[e], d = dst[e];
  float4 v = ((const float4*)(h + (size_t)s * HD))[ch];
  float* p = A + (size_t)d * HD + ch * 4;
  atomicAdd(p + 0, v.x);
  atomicAdd(p + 1, v.y);
  atomicAdd(p + 2, v.z);
  atomicAdd(p + 3, v.w);
}

// ---------------- generic fp32 GEMM: out[M,COLS] = A[M,K] @ W[K,COLS] + bias ----
// Safe for out == A (each block stages its own rows to LDS before any store;
// no __restrict__ on out/A pair).
template <int K, int COLS, int RPT, bool RELU>
__global__ __launch_bounds__(256) void k_gemm(const float* A,
    const float* __restrict__ W, const float* __restrict__ bias,
    float* out) {
  constexpr int CG = COLS / 4;
  constexpr int RG = 256 / CG;
  constexpr int TM = RG * RPT;
  __shared__ float As[TM * K];
  const int row0 = blockIdx.x * TM;
  const float4* A4 = (const float4*)(A + (size_t)row0 * K);
  float4* As4 = (float4*)As;
  for (int i = threadIdx.x; i < TM * K / 4; i += 256) As4[i] = A4[i];
  __syncthreads();
  const int cg = threadIdx.x % CG;
  const int rg = threadIdx.x / CG;
  const int r0 = rg * RPT;
  float acc[RPT][4] = {};
  const float4* W4 = (const float4*)W;
#pragma unroll 4
  for (int k = 0; k < K; k += 4) {
    float4 w0 = W4[(size_t)(k + 0) * CG + cg];
    float4 w1 = W4[(size_t)(k + 1) * CG + cg];
    float4 w2 = W4[(size_t)(k + 2) * CG + cg];
    float4 w3 = W4[(size_t)(k + 3) * CG + cg];
#pragma unroll
    for (int r = 0; r < RPT; ++r) {
      float4 a = As4[((r0 + r) * K + k) >> 2];
      acc[r][0] += a.x * w0.x + a.y * w1.x + a.z * w2.x + a.w * w3.x;
      acc[r][1] += a.x * w0.y + a.y * w1.y + a.z * w2.y + a.w * w3.y;
      acc[r][2] += a.x * w0.z + a.y * w1.z + a.z * w2.z + a.w * w3.z;
      acc[r][3] += a.x * w0.w + a.y * w1.w + a.z * w2.w + a.w * w3.w;
    }
  }
  float4 bv = ((const float4*)bias)[cg];
#pragma unroll
  for (int r = 0; r < RPT; ++r) {
    float4 o;
    o.x = acc[r][0] + bv.x;
    o.y = acc[r][1] + bv.y;
    o.z = acc[r][2] + bv.z;
    o.w = acc[r][3] + bv.w;
    if (RELU) {
      o.x = fmaxf(o.x, 0.f); o.y = fmaxf(o.y, 0.f);
      o.z = fmaxf(o.z, 0.f); o.w = fmaxf(o.w, 0.f);
    }
    ((float4*)(out + (size_t)(row0 + r0 + r) * COLS))[cg] = o;
  }
}

// ---------------- stage 1: per-block column sums / sumsq ----------------
__global__ __launch_bounds__(256) void k_stats1(const float* __restrict__ Z,
    float* __restrict__ partial) {
  int c = threadIdx.x & 127;
  int half = threadIdx.x >> 7;
  float s = 0.f, sq = 0.f;
  for (int n = blockIdx.x * 2 + half; n < NN; n += SBLK * 2) {
    float v = Z[(size_t)n * HD + c];
    s += v;
    sq += v * v;
  }
  __shared__ float ls[256], lq[256];
  ls[threadIdx.x] = s;
  lq[threadIdx.x] = sq;
  __syncthreads();
  if (threadIdx.x < 128) {
    partial[(size_t)blockIdx.x * 256 + threadIdx.x] =
        ls[threadIdx.x] + ls[threadIdx.x + 128];
    partial[(size_t)blockIdx.x * 256 + 128 + threadIdx.x] =
        lq[threadIdx.x] + lq[threadIdx.x + 128];
  }
}

// ---------------- stage 2: reduce partials -> stats[256] ----------------
__global__ __launch_bounds__(256) void k_stats2(const float* __restrict__ partial,
    float* __restrict__ stats) {
  int t = threadIdx.x;
  float acc = 0.f;
  for (int b = 0; b < SBLK; ++b) acc += partial[(size_t)b * 256 + t];
  stats[t] = acc;
}

// ---------------- BN(train stats) + ReLU ----------------
__global__ __launch_bounds__(256) void k_bn(const float4* __restrict__ Z4,
    const float* __restrict__ stats, const float* __restrict__ gamma,
    const float* __restrict__ beta, float4* __restrict__ h4) {
  int idx = blockIdx.x * 256 + threadIdx.x;
  if (idx >= NN * 32) return;
  int q = idx & 31;
  float4 z = Z4[idx];
  float4 s = ((const float4*)stats)[q];
  float4 sq = ((const float4*)stats)[32 + q];
  float4 gm = ((const float4*)gamma)[q];
  float4 bt = ((const float4*)beta)[q];
  const float invn = 1.f / NN;
  float4 o;
  float mu, var;
  mu = s.x * invn; var = sq.x * invn - mu * mu;
  o.x = fmaxf((z.x - mu) * rsqrtf(var + 1e-5f) * gm.x + bt.x, 0.f);
  mu = s.y * invn; var = sq.y * invn - mu * mu;
  o.y = fmaxf((z.y - mu) * rsqrtf(var + 1e-5f) * gm.y + bt.y, 0.f);
  mu = s.z * invn; var = sq.z * invn - mu * mu;
  o.z = fmaxf((z.z - mu) * rsqrtf(var + 1e-5f) * gm.z + bt.z, 0.f);
  mu = s.w * invn; var = sq.w * invn - mu * mu;
  o.w = fmaxf((z.w - mu) * rsqrtf(var + 1e-5f) * gm.w + bt.w, 0.f);
  h4[idx] = o;
}

// ---------------- zero helper ----------------
__global__ __launch_bounds__(256) void k_zero(float* __restrict__ p, int n) {
  int i = blockIdx.x * 256 + threadIdx.x;
  if (i < n) p[i] = 0.f;
}

// ---------------- pooling: segmented sum exploiting sorted batch ----------------
__global__ __launch_bounds__(128) void k_pool(const float* __restrict__ h,
    const int* __restrict__ batch, float* __restrict__ sums) {
  int c = threadIdx.x;
  int n0 = blockIdx.x * 64;
  int nend = n0 + 64;
  if (nend > NN) nend = NN;
  int curb = batch[n0];
  float acc = 0.f;
  for (int n = n0; n < nend; ++n) {
    int b = batch[n];
    if (b != curb) {
      atomicAdd(&sums[(size_t)curb * HD + c], acc);
      acc = 0.f;
      curb = b;
    }
    acc += h[(size_t)n * HD + c];
  }
  atomicAdd(&sums[(size_t)curb * HD + c], acc);
}

__global__ __launch_bounds__(256) void k_cnt(const int* __restrict__ batch,
    float* __restrict__ cnt) {
  int n = blockIdx.x * 256 + threadIdx.x;
  if (n < NN) atomicAdd(&cnt[batch[n]], 1.f);
}

__global__ __launch_bounds__(256) void k_div(const float4* __restrict__ sums4,
    const float* __restrict__ cnt, float4* __restrict__ g4) {
  int idx = blockIdx.x * 256 + threadIdx.x;
  if (idx >= NB * 32) return;
  int b = idx >> 5;
  float inv = 1.f / fmaxf(cnt[b], 1.f);
  float4 v = sums4[idx];
  g4[idx] = make_float4(v.x * inv, v.y * inv, v.z * inv, v.w * inv);
}

// ---------------- row L2 normalize (in-place safe): one wave per row --------
__global__ __launch_bounds__(256) void k_norm(float* g) {
  int wave = threadIdx.x >> 6, lane = threadIdx.x & 63;
  int row = blockIdx.x * 4 + wave;
  if (row >= NB) return;
  float2 v = ((const float2*)(g + (size_t)row * HD))[lane];
  float sq = v.x * v.x + v.y * v.y;
#pragma unroll
  for (int o = 32; o > 0; o >>= 1) sq += __shfl_xor(sq, o, 64);
  float inv = 1.f / fmaxf(sqrtf(sq), 1e-12f);
  ((float2*)(g + (size_t)row * HD))[lane] = make_float2(v.x * inv, v.y * inv);
}

extern "C" void kernel_launch(void* const* d_in, const int* in_sizes, int n_in,
                              void* d_out, int out_size, void* d_ws, size_t ws_size,
                              hipStream_t stream) {
  // required workspace (floats): h, A, g1, sums, cnt, partial, stats
  const size_t need = (size_t)NN * HD * 2 + (size_t)NB * PHD + (size_t)NB * HD
                      + NB + (size_t)SBLK * 256 + 256;
  if (ws_size < need * sizeof(float)) {
    // Workspace too small for this design: emit zeros as a clean diagnostic
    // (bench reports finite absmax instead of a memory-fault). Decision depends
    // only on ws_size (constant across calls) -> graph-capture safe.
    k_zero<<<(out_size + 255) / 256, 256, 0, stream>>>((float*)d_out, out_size);
    return;
  }

  const int* x = (const int*)d_in[0];
  const int* ei = (const int*)d_in[1];
  const int* batch = (const int*)d_in[2];
  const float* emb = (const float*)d_in[3];
  const float* eps = (const float*)d_in[4];
  const float* w1 = (const float*)d_in[5];
  const float* b1 = (const float*)d_in[6];
  const float* w2 = (const float*)d_in[7];
  const float* b2 = (const float*)d_in[8];
  const float* gamma = (const float*)d_in[9];
  const float* beta = (const float*)d_in[10];
  const float* pw1 = (const float*)d_in[11];
  const float* pb1 = (const float*)d_in[12];
  const float* pw2 = (const float*)d_in[13];
  const float* pb2 = (const float*)d_in[14];
  float* out = (float*)d_out;

  // workspace layout (floats): 2 big buffers + small scratch = ~226 MB
  float* h = (float*)d_ws;                        // NN*HD      = 25.6M
  float* A = h + (size_t)NN * HD;                 // NN*HD      = 25.6M
  float* g1 = A + (size_t)NN * HD;                // NB*PHD     = 4.096M
  float* sums = g1 + (size_t)NB * PHD;            // NB*HD      = 1.024M
  float* cnt = sums + (size_t)NB * HD;            // NB
  float* partial = cnt + NB;                      // SBLK*256   = 262144
  float* stats = partial + (size_t)SBLK * 256;    // 256
  float* g = out;                                 // NB*HD lives in d_out

  const int* src = ei;
  const int* dst = ei + NE;

  k_encoder<<<(NN * HD + 255) / 256, 256, 0, stream>>>(x, emb, h);

  for (int l = 0; l < NL; ++l) {
    k_init_a<<<(NN * HD / 4 + 255) / 256, 256, 0, stream>>>(
        (const float4*)h, eps, l, (float4*)A);
    k_scatter<<<(NE * 32 + 255) / 256, 256, 0, stream>>>(src, dst, h, A);
    // in-place: A = relu(A@w1+b1); A = A@w2+b2
    k_gemm<128, 128, 8, true><<<NN / 64, 256, 0, stream>>>(
        A, w1 + (size_t)l * HD * HD, b1 + (size_t)l * HD, A);
    k_gemm<128, 128, 8, false><<<NN / 64, 256, 0, stream>>>(
        A, w2 + (size_t)l * HD * HD, b2 + (size_t)l * HD, A);
    k_stats1<<<SBLK, 256, 0, stream>>>(A, partial);
    k_stats2<<<1, 256, 0, stream>>>(partial, stats);
    k_bn<<<(NN * 32 + 255) / 256, 256, 0, stream>>>(
        (const float4*)A, stats, gamma + (size_t)l * HD, beta + (size_t)l * HD,
        (float4*)h);
  }

  k_zero<<<(NB * HD + NB + 255) / 256, 256, 0, stream>>>(sums, NB * HD + NB);
  k_pool<<<NN / 64, 128, 0, stream>>>(h, batch, sums);
  k_cnt<<<(NN + 255) / 256, 256, 0, stream>>>(batch, cnt);
  k_div<<<(NB * 32 + 255) / 256, 256, 0, stream>>>(
      (const float4*)sums, cnt, (float4*)g);

  k_gemm<128, 512, 8, true><<<NB / 16, 256, 0, stream>>>(g, pw1, pb1, g1);
  k_gemm<512, 128, 2, false><<<NB / 16, 256, 0, stream>>>(g1, pw2, pb2, g);
  k_norm<<<(NB + 3) / 4, 256, 0, stream>>>(g);
}

// Round 9
// 2394.697 us; speedup vs baseline: 3.0707x; 3.0707x over previous
//
#include <hip/hip_runtime.h>

#define NN 200000     // nodes
#define NE 640000     // edges
#define HD 128        // hidden
#define NL 5          // layers
#define PHD 512       // proj hidden
#define NB 8000       // graphs
#define MAXV 119
#define SBLK 1024     // stats partial blocks
#define NBLK 782      // ceil(NN/256) scan blocks

// ---------------- AtomEncoder: h[n,c] = sum_s emb[s, x[n,s], c] ----------------
__global__ __launch_bounds__(256) void k_encoder(const int* __restrict__ x,
    const float* __restrict__ emb, float* __restrict__ h) {
  int idx = blockIdx.x * 256 + threadIdx.x;
  if (idx >= NN * HD) return;
  int n = idx >> 7, c = idx & 127;
  const int* xr = x + n * 9;
  float acc = 0.f;
#pragma unroll
  for (int s = 0; s < 9; ++s)
    acc += emb[(s * MAXV + xr[s]) * HD + c];
  h[idx] = acc;
}

// ================= CSR build (once per call; graph constant across layers) ====
__global__ __launch_bounds__(256) void k_zero_int(int* __restrict__ p, int n) {
  int i = blockIdx.x * 256 + threadIdx.x;
  if (i < n) p[i] = 0;
}

__global__ __launch_bounds__(256) void k_hist(const int* __restrict__ dst,
    int* __restrict__ deg) {
  int e = blockIdx.x * 256 + threadIdx.x;
  if (e < NE) atomicAdd(&deg[dst[e]], 1);
}

// block-local exclusive scan of deg -> rowptr (block-local), block totals out
__global__ __launch_bounds__(256) void k_scan1(const int* __restrict__ deg,
    int* __restrict__ rowptr, int* __restrict__ blksum) {
  int t = threadIdx.x;
  int i = blockIdx.x * 256 + t;
  int v = (i < NN) ? deg[i] : 0;
  __shared__ int s[256];
  s[t] = v;
  __syncthreads();
  for (int off = 1; off < 256; off <<= 1) {
    int x = (t >= off) ? s[t - off] : 0;
    __syncthreads();
    s[t] += x;
    __syncthreads();
  }
  if (i < NN) rowptr[i] = s[t] - v;     // exclusive within block
  if (t == 255) blksum[blockIdx.x] = s[255];
}

// single block: exclusive scan of NBLK block totals (4 elems/thread, chunked)
__global__ __launch_bounds__(256) void k_scan2(const int* __restrict__ blksum,
    int* __restrict__ blkoff) {
  int t = threadIdx.x;
  int base = t * 4;
  int v[4];
#pragma unroll
  for (int k = 0; k < 4; ++k) v[k] = (base + k < NBLK) ? blksum[base + k] : 0;
  int p1 = v[0], p2 = p1 + v[1], p3 = p2 + v[2], tot = p3 + v[3];
  __shared__ int s[256];
  s[t] = tot;
  __syncthreads();
  for (int off = 1; off < 256; off <<= 1) {
    int x = (t >= off) ? s[t - off] : 0;
    __syncthreads();
    s[t] += x;
    __syncthreads();
  }
  int excl = s[t] - tot;
  if (base + 0 < NBLK) blkoff[base + 0] = excl;
  if (base + 1 < NBLK) blkoff[base + 1] = excl + p1;
  if (base + 2 < NBLK) blkoff[base + 2] = excl + p2;
  if (base + 3 < NBLK) blkoff[base + 3] = excl + p3;
}

__global__ __launch_bounds__(256) void k_scan3(int* __restrict__ rowptr,
    const int* __restrict__ blkoff) {
  int i = blockIdx.x * 256 + threadIdx.x;
  if (i < NN) rowptr[i] += blkoff[blockIdx.x];
  if (i == 0) rowptr[NN] = NE;
}

__global__ __launch_bounds__(256) void k_fill(const int* __restrict__ src,
    const int* __restrict__ dst, const int* __restrict__ rowptr,
    int* __restrict__ cur, int* __restrict__ csr_src) {
  int e = blockIdx.x * 256 + threadIdx.x;
  if (e >= NE) return;
  int d = dst[e];
  int pos = rowptr[d] + atomicAdd(&cur[d], 1);
  csr_src[pos] = src[e];
}

// ======== fused GIN aggregate: A[i,:] = (1+eps)h[i,:] + sum_nbr h[j,:] ========
// one wave (64 lanes x float2) per node; no atomics, coalesced 512B row reads
__global__ __launch_bounds__(256) void k_agg(const float* __restrict__ h,
    const int* __restrict__ rowptr, const int* __restrict__ csr_src,
    const float* __restrict__ eps, int l, float* __restrict__ A) {
  int gid = blockIdx.x * 256 + threadIdx.x;
  int node = gid >> 6, lane = gid & 63;
  if (node >= NN) return;
  float e = 1.f + eps[l];
  float2 v = ((const float2*)(h + (size_t)node * HD))[lane];
  float2 acc = make_float2(e * v.x, e * v.y);
  int beg = rowptr[node], end = rowptr[node + 1];
  for (int t = beg; t < end; ++t) {
    int j = csr_src[t];
    float2 u = ((const float2*)(h + (size_t)j * HD))[lane];
    acc.x += u.x;
    acc.y += u.y;
  }
  ((float2*)(A + (size_t)node * HD))[lane] = acc;
}

// ---------------- generic fp32 GEMM: out[M,COLS] = A[M,K] @ W[K,COLS] + bias ----
// Safe for out == A (each block stages its own rows to LDS before any store).
template <int K, int COLS, int RPT, bool RELU>
__global__ __launch_bounds__(256) void k_gemm(const float* A,
    const float* __restrict__ W, const float* __restrict__ bias,
    float* out) {
  constexpr int CG = COLS / 4;
  constexpr int RG = 256 / CG;
  constexpr int TM = RG * RPT;
  __shared__ float As[TM * K];
  const int row0 = blockIdx.x * TM;
  const float4* A4 = (const float4*)(A + (size_t)row0 * K);
  float4* As4 = (float4*)As;
  for (int i = threadIdx.x; i < TM * K / 4; i += 256) As4[i] = A4[i];
  __syncthreads();
  const int cg = threadIdx.x % CG;
  const int rg = threadIdx.x / CG;
  const int r0 = rg * RPT;
  float acc[RPT][4] = {};
  const float4* W4 = (const float4*)W;
#pragma unroll 4
  for (int k = 0; k < K; k += 4) {
    float4 w0 = W4[(size_t)(k + 0) * CG + cg];
    float4 w1 = W4[(size_t)(k + 1) * CG + cg];
    float4 w2 = W4[(size_t)(k + 2) * CG + cg];
    float4 w3 = W4[(size_t)(k + 3) * CG + cg];
#pragma unroll
    for (int r = 0; r < RPT; ++r) {
      float4 a = As4[((r0 + r) * K + k) >> 2];
      acc[r][0] += a.x * w0.x + a.y * w1.x + a.z * w2.x + a.w * w3.x;
      acc[r][1] += a.x * w0.y + a.y * w1.y + a.z * w2.y + a.w * w3.y;
      acc[r][2] += a.x * w0.z + a.y * w1.z + a.z * w2.z + a.w * w3.z;
      acc[r][3] += a.x * w0.w + a.y * w1.w + a.z * w2.w + a.w * w3.w;
    }
  }
  float4 bv = ((const float4*)bias)[cg];
#pragma unroll
  for (int r = 0; r < RPT; ++r) {
    float4 o;
    o.x = acc[r][0] + bv.x;
    o.y = acc[r][1] + bv.y;
    o.z = acc[r][2] + bv.z;
    o.w = acc[r][3] + bv.w;
    if (RELU) {
      o.x = fmaxf(o.x, 0.f); o.y = fmaxf(o.y, 0.f);
      o.z = fmaxf(o.z, 0.f); o.w = fmaxf(o.w, 0.f);
    }
    ((float4*)(out + (size_t)(row0 + r0 + r) * COLS))[cg] = o;
  }
}

// ---------------- stage 1: per-block column sums / sumsq ----------------
__global__ __launch_bounds__(256) void k_stats1(const float* __restrict__ Z,
    float* __restrict__ partial) {
  int c = threadIdx.x & 127;
  int half = threadIdx.x >> 7;
  float s = 0.f, sq = 0.f;
  for (int n = blockIdx.x * 2 + half; n < NN; n += SBLK * 2) {
    float v = Z[(size_t)n * HD + c];
    s += v;
    sq += v * v;
  }
  __shared__ float ls[256], lq[256];
  ls[threadIdx.x] = s;
  lq[threadIdx.x] = sq;
  __syncthreads();
  if (threadIdx.x < 128) {
    partial[(size_t)blockIdx.x * 256 + threadIdx.x] =
        ls[threadIdx.x] + ls[threadIdx.x + 128];
    partial[(size_t)blockIdx.x * 256 + 128 + threadIdx.x] =
        lq[threadIdx.x] + lq[threadIdx.x + 128];
  }
}

// ---------------- stage 2: reduce partials -> stats[256] ----------------
__global__ __launch_bounds__(256) void k_stats2(const float* __restrict__ partial,
    float* __restrict__ stats) {
  int t = threadIdx.x;
  float acc = 0.f;
  for (int b = 0; b < SBLK; ++b) acc += partial[(size_t)b * 256 + t];
  stats[t] = acc;
}

// ---------------- BN(train stats) + ReLU ----------------
__global__ __launch_bounds__(256) void k_bn(const float4* __restrict__ Z4,
    const float* __restrict__ stats, const float* __restrict__ gamma,
    const float* __restrict__ beta, float4* __restrict__ h4) {
  int idx = blockIdx.x * 256 + threadIdx.x;
  if (idx >= NN * 32) return;
  int q = idx & 31;
  float4 z = Z4[idx];
  float4 s = ((const float4*)stats)[q];
  float4 sq = ((const float4*)stats)[32 + q];
  float4 gm = ((const float4*)gamma)[q];
  float4 bt = ((const float4*)beta)[q];
  const float invn = 1.f / NN;
  float4 o;
  float mu, var;
  mu = s.x * invn; var = sq.x * invn - mu * mu;
  o.x = fmaxf((z.x - mu) * rsqrtf(var + 1e-5f) * gm.x + bt.x, 0.f);
  mu = s.y * invn; var = sq.y * invn - mu * mu;
  o.y = fmaxf((z.y - mu) * rsqrtf(var + 1e-5f) * gm.y + bt.y, 0.f);
  mu = s.z * invn; var = sq.z * invn - mu * mu;
  o.z = fmaxf((z.z - mu) * rsqrtf(var + 1e-5f) * gm.z + bt.z, 0.f);
  mu = s.w * invn; var = sq.w * invn - mu * mu;
  o.w = fmaxf((z.w - mu) * rsqrtf(var + 1e-5f) * gm.w + bt.w, 0.f);
  h4[idx] = o;
}

// ---------------- zero helper ----------------
__global__ __launch_bounds__(256) void k_zero(float* __restrict__ p, int n) {
  int i = blockIdx.x * 256 + threadIdx.x;
  if (i < n) p[i] = 0.f;
}

// ---------------- pooling: segmented sum exploiting sorted batch ----------------
__global__ __launch_bounds__(128) void k_pool(const float* __restrict__ h,
    const int* __restrict__ batch, float* __restrict__ sums) {
  int c = threadIdx.x;
  int n0 = blockIdx.x * 64;
  int nend = n0 + 64;
  if (nend > NN) nend = NN;
  int curb = batch[n0];
  float acc = 0.f;
  for (int n = n0; n < nend; ++n) {
    int b = batch[n];
    if (b != curb) {
      atomicAdd(&sums[(size_t)curb * HD + c], acc);
      acc = 0.f;
      curb = b;
    }
    acc += h[(size_t)n * HD + c];
  }
  atomicAdd(&sums[(size_t)curb * HD + c], acc);
}

__global__ __launch_bounds__(256) void k_cnt(const int* __restrict__ batch,
    float* __restrict__ cnt) {
  int n = blockIdx.x * 256 + threadIdx.x;
  if (n < NN) atomicAdd(&cnt[batch[n]], 1.f);
}

__global__ __launch_bounds__(256) void k_div(const float4* __restrict__ sums4,
    const float* __restrict__ cnt, float4* __restrict__ g4) {
  int idx = blockIdx.x * 256 + threadIdx.x;
  if (idx >= NB * 32) return;
  int b = idx >> 5;
  float inv = 1.f / fmaxf(cnt[b], 1.f);
  float4 v = sums4[idx];
  g4[idx] = make_float4(v.x * inv, v.y * inv, v.z * inv, v.w * inv);
}

// ---------------- row L2 normalize (in-place safe): one wave per row --------
__global__ __launch_bounds__(256) void k_norm(float* g) {
  int wave = threadIdx.x >> 6, lane = threadIdx.x & 63;
  int row = blockIdx.x * 4 + wave;
  if (row >= NB) return;
  float2 v = ((const float2*)(g + (size_t)row * HD))[lane];
  float sq = v.x * v.x + v.y * v.y;
#pragma unroll
  for (int o = 32; o > 0; o >>= 1) sq += __shfl_xor(sq, o, 64);
  float inv = 1.f / fmaxf(sqrtf(sq), 1e-12f);
  ((float2*)(g + (size_t)row * HD))[lane] = make_float2(v.x * inv, v.y * inv);
}

extern "C" void kernel_launch(void* const* d_in, const int* in_sizes, int n_in,
                              void* d_out, int out_size, void* d_ws, size_t ws_size,
                              hipStream_t stream) {
  // required workspace (floats) — identical to the passing round-5 layout;
  // CSR arrays alias into g1's region (disjoint lifetime).
  const size_t need = (size_t)NN * HD * 2 + (size_t)NB * PHD + (size_t)NB * HD
                      + NB + (size_t)SBLK * 256 + 256;
  if (ws_size < need * sizeof(float)) {
    k_zero<<<(out_size + 255) / 256, 256, 0, stream>>>((float*)d_out, out_size);
    return;
  }

  const int* x = (const int*)d_in[0];
  const int* ei = (const int*)d_in[1];
  const int* batch = (const int*)d_in[2];
  const float* emb = (const float*)d_in[3];
  const float* eps = (const float*)d_in[4];
  const float* w1 = (const float*)d_in[5];
  const float* b1 = (const float*)d_in[6];
  const float* w2 = (const float*)d_in[7];
  const float* b2 = (const float*)d_in[8];
  const float* gamma = (const float*)d_in[9];
  const float* beta = (const float*)d_in[10];
  const float* pw1 = (const float*)d_in[11];
  const float* pb1 = (const float*)d_in[12];
  const float* pw2 = (const float*)d_in[13];
  const float* pb2 = (const float*)d_in[14];
  float* out = (float*)d_out;

  float* h = (float*)d_ws;                        // NN*HD
  float* A = h + (size_t)NN * HD;                 // NN*HD
  float* g1 = A + (size_t)NN * HD;                // NB*PHD (proj scratch, late)
  float* sums = g1 + (size_t)NB * PHD;            // NB*HD
  float* cnt = sums + (size_t)NB * HD;            // NB
  float* partial = cnt + NB;                      // SBLK*256
  float* stats = partial + (size_t)SBLK * 256;    // 256
  float* g = out;                                 // NB*HD in d_out

  // CSR arrays alias g1 (used only during layers; g1 only after pooling)
  int* rowptr = (int*)g1;                         // NN+1
  int* cur = rowptr + NN + 1;                     // NN (deg, then fill cursor)
  int* blksum = cur + NN;                         // NBLK (<=1024)
  int* blkoff = blksum + 1024;                    // NBLK
  int* csr_src = blkoff + 1024;                   // NE

  const int* src = ei;
  const int* dst = ei + NE;

  // ---- build CSR by destination (once; reused by all 5 layers) ----
  k_zero_int<<<(NN + 255) / 256, 256, 0, stream>>>(cur, NN);
  k_hist<<<(NE + 255) / 256, 256, 0, stream>>>(dst, cur);
  k_scan1<<<NBLK, 256, 0, stream>>>(cur, rowptr, blksum);
  k_scan2<<<1, 256, 0, stream>>>(blksum, blkoff);
  k_scan3<<<NBLK, 256, 0, stream>>>(rowptr, blkoff);
  k_zero_int<<<(NN + 255) / 256, 256, 0, stream>>>(cur, NN);
  k_fill<<<(NE + 255) / 256, 256, 0, stream>>>(src, dst, rowptr, cur, csr_src);

  k_encoder<<<(NN * HD + 255) / 256, 256, 0, stream>>>(x, emb, h);

  for (int l = 0; l < NL; ++l) {
    // fused (1+eps)*h + neighbor gather-sum (replaces init_a + atomic scatter)
    k_agg<<<(NN * 64 + 255) / 256, 256, 0, stream>>>(h, rowptr, csr_src, eps, l, A);
    // in-place: A = relu(A@w1+b1); A = A@w2+b2
    k_gemm<128, 128, 8, true><<<NN / 64, 256, 0, stream>>>(
        A, w1 + (size_t)l * HD * HD, b1 + (size_t)l * HD, A);
    k_gemm<128, 128, 8, false><<<NN / 64, 256, 0, stream>>>(
        A, w2 + (size_t)l * HD * HD, b2 + (size_t)l * HD, A);
    k_stats1<<<SBLK, 256, 0, stream>>>(A, partial);
    k_stats2<<<1, 256, 0, stream>>>(partial, stats);
    k_bn<<<(NN * 32 + 255) / 256, 256, 0, stream>>>(
        (const float4*)A, stats, gamma + (size_t)l * HD, beta + (size_t)l * HD,
        (float4*)h);
  }

  k_zero<<<(NB * HD + NB + 255) / 256, 256, 0, stream>>>(sums, NB * HD + NB);
  k_pool<<<NN / 64, 128, 0, stream>>>(h, batch, sums);
  k_cnt<<<(NN + 255) / 256, 256, 0, stream>>>(batch, cnt);
  k_div<<<(NB * 32 + 255) / 256, 256, 0, stream>>>(
      (const float4*)sums, cnt, (float4*)g);

  k_gemm<128, 512, 8, true><<<NB / 16, 256, 0, stream>>>(g, pw1, pb1, g1);
  k_gemm<512, 128, 2, false><<<NB / 16, 256, 0, stream>>>(g1, pw2, pb2, g);
  k_norm<<<(NB + 3) / 4, 256, 0, stream>>>(g);
}

// Round 13
// 1747.183 us; speedup vs baseline: 4.2087x; 1.3706x over previous
//
#include <hip/hip_runtime.h>

#define NN 200000     // nodes
#define NE 640000     // edges
#define HD 128        // hidden
#define NL 5          // layers
#define PHD 512       // proj hidden
#define NB 8000       // graphs
#define MAXV 119
#define SBLK 1024     // stats partial blocks
#define NBLK 782      // ceil(NN/256) scan blocks

typedef short bf16x8 __attribute__((ext_vector_type(8)));
typedef float f32x4 __attribute__((ext_vector_type(4)));

// split fp32 -> bf16 hi (truncate) + bf16 lo (RNE of exact residual).
// f == float(hi<<16) + fl exactly; lo = RNE16(fl) -> total err ~2^-17 |f|.
__device__ __forceinline__ void split_bf16(float f, short& hi, short& lo) {
  unsigned u = __float_as_uint(f);
  hi = (short)(u >> 16);
  float fh = __uint_as_float(u & 0xffff0000u);
  float fl = f - fh;
  unsigned ul = __float_as_uint(fl);
  lo = (short)((ul + 0x7fffu + ((ul >> 16) & 1u)) >> 16);
}

// ---------------- AtomEncoder: h[n,c] = sum_s emb[s, x[n,s], c] ----------------
__global__ __launch_bounds__(256) void k_encoder(const int* __restrict__ x,
    const float* __restrict__ emb, float* __restrict__ h) {
  int idx = blockIdx.x * 256 + threadIdx.x;
  if (idx >= NN * HD) return;
  int n = idx >> 7, c = idx & 127;
  const int* xr = x + n * 9;
  float acc = 0.f;
#pragma unroll
  for (int s = 0; s < 9; ++s)
    acc += emb[(s * MAXV + xr[s]) * HD + c];
  h[idx] = acc;
}

// ================= CSR build (once per call; graph constant across layers) ====
__global__ __launch_bounds__(256) void k_zero_int(int* __restrict__ p, int n) {
  int i = blockIdx.x * 256 + threadIdx.x;
  if (i < n) p[i] = 0;
}

__global__ __launch_bounds__(256) void k_hist(const int* __restrict__ dst,
    int* __restrict__ deg) {
  int e = blockIdx.x * 256 + threadIdx.x;
  if (e < NE) atomicAdd(&deg[dst[e]], 1);
}

__global__ __launch_bounds__(256) void k_scan1(const int* __restrict__ deg,
    int* __restrict__ rowptr, int* __restrict__ blksum) {
  int t = threadIdx.x;
  int i = blockIdx.x * 256 + t;
  int v = (i < NN) ? deg[i] : 0;
  __shared__ int s[256];
  s[t] = v;
  __syncthreads();
  for (int off = 1; off < 256; off <<= 1) {
    int x = (t >= off) ? s[t - off] : 0;
    __syncthreads();
    s[t] += x;
    __syncthreads();
  }
  if (i < NN) rowptr[i] = s[t] - v;
  if (t == 255) blksum[blockIdx.x] = s[255];
}

__global__ __launch_bounds__(256) void k_scan2(const int* __restrict__ blksum,
    int* __restrict__ blkoff) {
  int t = threadIdx.x;
  int base = t * 4;
  int v[4];
#pragma unroll
  for (int k = 0; k < 4; ++k) v[k] = (base + k < NBLK) ? blksum[base + k] : 0;
  int p1 = v[0], p2 = p1 + v[1], p3 = p2 + v[2], tot = p3 + v[3];
  __shared__ int s[256];
  s[t] = tot;
  __syncthreads();
  for (int off = 1; off < 256; off <<= 1) {
    int x = (t >= off) ? s[t - off] : 0;
    __syncthreads();
    s[t] += x;
    __syncthreads();
  }
  int excl = s[t] - tot;
  if (base + 0 < NBLK) blkoff[base + 0] = excl;
  if (base + 1 < NBLK) blkoff[base + 1] = excl + p1;
  if (base + 2 < NBLK) blkoff[base + 2] = excl + p2;
  if (base + 3 < NBLK) blkoff[base + 3] = excl + p3;
}

__global__ __launch_bounds__(256) void k_scan3(int* __restrict__ rowptr,
    const int* __restrict__ blkoff) {
  int i = blockIdx.x * 256 + threadIdx.x;
  if (i < NN) rowptr[i] += blkoff[blockIdx.x];
  if (i == 0) rowptr[NN] = NE;
}

__global__ __launch_bounds__(256) void k_fill(const int* __restrict__ src,
    const int* __restrict__ dst, const int* __restrict__ rowptr,
    int* __restrict__ cur, int* __restrict__ csr_src) {
  int e = blockIdx.x * 256 + threadIdx.x;
  if (e >= NE) return;
  int d = dst[e];
  int pos = rowptr[d] + atomicAdd(&cur[d], 1);
  csr_src[pos] = src[e];
}

// ======== fused GIN aggregate: A[i,:] = (1+eps)h[i,:] + sum_nbr h[j,:] ========
__global__ __launch_bounds__(256) void k_agg(const float* __restrict__ h,
    const int* __restrict__ rowptr, const int* __restrict__ csr_src,
    const float* __restrict__ eps, int l, float* __restrict__ A) {
  int gid = blockIdx.x * 256 + threadIdx.x;
  int node = gid >> 6, lane = gid & 63;
  if (node >= NN) return;
  float e = 1.f + eps[l];
  float2 v = ((const float2*)(h + (size_t)node * HD))[lane];
  float2 acc = make_float2(e * v.x, e * v.y);
  int beg = rowptr[node], end = rowptr[node + 1];
  for (int t = beg; t < end; ++t) {
    int j = csr_src[t];
    float2 u = ((const float2*)(h + (size_t)j * HD))[lane];
    acc.x += u.x;
    acc.y += u.y;
  }
  ((float2*)(A + (size_t)node * HD))[lane] = acc;
}

// ==== pre-split & pack weights into MFMA fragment order (once per call) ====
// wpk layout per (l,mat): [half(2)][kk(4)][nt(8)][lane(64)][j(8)] shorts
__global__ __launch_bounds__(256) void k_convw(const float* __restrict__ w1,
    const float* __restrict__ w2, short* __restrict__ wpk) {
  int idx = blockIdx.x * 256 + threadIdx.x;
  if (idx >= NL * 2 * 16384) return;
  int l = idx / (2 * 16384);
  int rem = idx % (2 * 16384);
  int mat = rem / 16384;
  int e = rem % 16384;
  int k = e >> 7, n = e & 127;
  float f = (mat ? w2 : w1)[(size_t)l * 16384 + e];
  short hi, lo;
  split_bf16(f, hi, lo);
  int kk = k >> 5, j = k & 7, kg = (k >> 3) & 3, nt = n >> 4, nc = n & 15;
  int lane = (kg << 4) | nc;
  size_t fo = (((size_t)kk * 8 + nt) * 64 + lane) * 8 + j;
  size_t base = (size_t)(l * 2 + mat) * 32768;
  wpk[base + fo] = hi;
  wpk[base + 16384 + fo] = lo;
}

// ==== node GEMM via MFMA bf16x3: out[M,128] = A[M,128]@W + bias (+ReLU) ====
// 4 waves/block, 16 rows/wave, no LDS, in-place safe (wave owns its rows).
// Frag layout: A m=lane&15,k=8*(lane>>4)+j; B n=lane&15; D col=lane&15,
// row=4*(lane>>4)+r  [m89-verified C/D].
template <bool RELU>
__global__ __launch_bounds__(256) void k_gemm_mfma(const float* A,
    const short* __restrict__ wpk_mat, const float* __restrict__ bias,
    float* out) {
  const int lane = threadIdx.x & 63;
  const int wid = threadIdx.x >> 6;
  const size_t row0 = (size_t)blockIdx.x * 64 + wid * 16;
  const int mrow = lane & 15;
  const int kg = lane >> 4;
  const float* Arow = A + (row0 + mrow) * HD;
  const bf16x8* wb = (const bf16x8*)wpk_mat;   // hi frags; lo at +2048

  f32x4 acc[8];
#pragma unroll
  for (int i = 0; i < 8; ++i) {
    acc[i][0] = 0.f; acc[i][1] = 0.f; acc[i][2] = 0.f; acc[i][3] = 0.f;
  }

#pragma unroll
  for (int kk = 0; kk < 4; ++kk) {
    const int kbase = kk * 32 + kg * 8;
    float4 a0 = *(const float4*)(Arow + kbase);
    float4 a1 = *(const float4*)(Arow + kbase + 4);
    float av[8] = {a0.x, a0.y, a0.z, a0.w, a1.x, a1.y, a1.z, a1.w};
    bf16x8 ahi, alo;
#pragma unroll
    for (int j = 0; j < 8; ++j) {
      short hi, lo;
      split_bf16(av[j], hi, lo);
      ahi[j] = hi;
      alo[j] = lo;
    }
#pragma unroll
    for (int nt = 0; nt < 8; ++nt) {
      int f = (kk * 8 + nt) * 64 + lane;
      bf16x8 whi = wb[f];
      bf16x8 wlo = wb[2048 + f];
      acc[nt] = __builtin_amdgcn_mfma_f32_16x16x32_bf16(alo, whi, acc[nt], 0, 0, 0);
      acc[nt] = __builtin_amdgcn_mfma_f32_16x16x32_bf16(ahi, wlo, acc[nt], 0, 0, 0);
      acc[nt] = __builtin_amdgcn_mfma_f32_16x16x32_bf16(ahi, whi, acc[nt], 0, 0, 0);
    }
  }

  const int m0 = kg * 4;
  const int nc = lane & 15;
#pragma unroll
  for (int nt = 0; nt < 8; ++nt) {
    float bv = bias[nt * 16 + nc];
#pragma unroll
    for (int r = 0; r < 4; ++r) {
      float v = acc[nt][r] + bv;
      if (RELU) v = fmaxf(v, 0.f);
      out[(row0 + m0 + r) * HD + nt * 16 + nc] = v;
    }
  }
}

// ---------------- generic fp32 GEMM (kept for projection head) ----------------
template <int K, int COLS, int RPT, bool RELU>
__global__ __launch_bounds__(256) void k_gemm(const float* A,
    const float* __restrict__ W, const float* __restrict__ bias,
    float* out) {
  constexpr int CG = COLS / 4;
  constexpr int RG = 256 / CG;
  constexpr int TM = RG * RPT;
  __shared__ float As[TM * K];
  const int row0 = blockIdx.x * TM;
  const float4* A4 = (const float4*)(A + (size_t)row0 * K);
  float4* As4 = (float4*)As;
  for (int i = threadIdx.x; i < TM * K / 4; i += 256) As4[i] = A4[i];
  __syncthreads();
  const int cg = threadIdx.x % CG;
  const int rg = threadIdx.x / CG;
  const int r0 = rg * RPT;
  float acc[RPT][4] = {};
  const float4* W4 = (const float4*)W;
#pragma unroll 4
  for (int k = 0; k < K; k += 4) {
    float4 w0 = W4[(size_t)(k + 0) * CG + cg];
    float4 w1 = W4[(size_t)(k + 1) * CG + cg];
    float4 w2 = W4[(size_t)(k + 2) * CG + cg];
    float4 w3 = W4[(size_t)(k + 3) * CG + cg];
#pragma unroll
    for (int r = 0; r < RPT; ++r) {
      float4 a = As4[((r0 + r) * K + k) >> 2];
      acc[r][0] += a.x * w0.x + a.y * w1.x + a.z * w2.x + a.w * w3.x;
      acc[r][1] += a.x * w0.y + a.y * w1.y + a.z * w2.y + a.w * w3.y;
      acc[r][2] += a.x * w0.z + a.y * w1.z + a.z * w2.z + a.w * w3.z;
      acc[r][3] += a.x * w0.w + a.y * w1.w + a.z * w2.w + a.w * w3.w;
    }
  }
  float4 bv = ((const float4*)bias)[cg];
#pragma unroll
  for (int r = 0; r < RPT; ++r) {
    float4 o;
    o.x = acc[r][0] + bv.x;
    o.y = acc[r][1] + bv.y;
    o.z = acc[r][2] + bv.z;
    o.w = acc[r][3] + bv.w;
    if (RELU) {
      o.x = fmaxf(o.x, 0.f); o.y = fmaxf(o.y, 0.f);
      o.z = fmaxf(o.z, 0.f); o.w = fmaxf(o.w, 0.f);
    }
    ((float4*)(out + (size_t)(row0 + r0 + r) * COLS))[cg] = o;
  }
}

// ---------------- stage 1: per-block column sums / sumsq ----------------
__global__ __launch_bounds__(256) void k_stats1(const float* __restrict__ Z,
    float* __restrict__ partial) {
  int c = threadIdx.x & 127;
  int half = threadIdx.x >> 7;
  float s = 0.f, sq = 0.f;
  for (int n = blockIdx.x * 2 + half; n < NN; n += SBLK * 2) {
    float v = Z[(size_t)n * HD + c];
    s += v;
    sq += v * v;
  }
  __shared__ float ls[256], lq[256];
  ls[threadIdx.x] = s;
  lq[threadIdx.x] = sq;
  __syncthreads();
  if (threadIdx.x < 128) {
    partial[(size_t)blockIdx.x * 256 + threadIdx.x] =
        ls[threadIdx.x] + ls[threadIdx.x + 128];
    partial[(size_t)blockIdx.x * 256 + 128 + threadIdx.x] =
        lq[threadIdx.x] + lq[threadIdx.x + 128];
  }
}

__global__ __launch_bounds__(256) void k_stats2(const float* __restrict__ partial,
    float* __restrict__ stats) {
  int t = threadIdx.x;
  float acc = 0.f;
  for (int b = 0; b < SBLK; ++b) acc += partial[(size_t)b * 256 + t];
  stats[t] = acc;
}

// ---------------- BN(train stats) + ReLU ----------------
__global__ __launch_bounds__(256) void k_bn(const float4* __restrict__ Z4,
    const float* __restrict__ stats, const float* __restrict__ gamma,
    const float* __restrict__ beta, float4* __restrict__ h4) {
  int idx = blockIdx.x * 256 + threadIdx.x;
  if (idx >= NN * 32) return;
  int q = idx & 31;
  float4 z = Z4[idx];
  float4 s = ((const float4*)stats)[q];
  float4 sq = ((const float4*)stats)[32 + q];
  float4 gm = ((const float4*)gamma)[q];
  float4 bt = ((const float4*)beta)[q];
  const float invn = 1.f / NN;
  float4 o;
  float mu, var;
  mu = s.x * invn; var = sq.x * invn - mu * mu;
  o.x = fmaxf((z.x - mu) * rsqrtf(var + 1e-5f) * gm.x + bt.x, 0.f);
  mu = s.y * invn; var = sq.y * invn - mu * mu;
  o.y = fmaxf((z.y - mu) * rsqrtf(var + 1e-5f) * gm.y + bt.y, 0.f);
  mu = s.z * invn; var = sq.z * invn - mu * mu;
  o.z = fmaxf((z.z - mu) * rsqrtf(var + 1e-5f) * gm.z + bt.z, 0.f);
  mu = s.w * invn; var = sq.w * invn - mu * mu;
  o.w = fmaxf((z.w - mu) * rsqrtf(var + 1e-5f) * gm.w + bt.w, 0.f);
  h4[idx] = o;
}

// ---------------- zero helper ----------------
__global__ __launch_bounds__(256) void k_zero(float* __restrict__ p, int n) {
  int i = blockIdx.x * 256 + threadIdx.x;
  if (i < n) p[i] = 0.f;
}

// ---------------- pooling: segmented sum exploiting sorted batch ----------------
__global__ __launch_bounds__(128) void k_pool(const float* __restrict__ h,
    const int* __restrict__ batch, float* __restrict__ sums) {
  int c = threadIdx.x;
  int n0 = blockIdx.x * 64;
  int nend = n0 + 64;
  if (nend > NN) nend = NN;
  int curb = batch[n0];
  float acc = 0.f;
  for (int n = n0; n < nend; ++n) {
    int b = batch[n];
    if (b != curb) {
      atomicAdd(&sums[(size_t)curb * HD + c], acc);
      acc = 0.f;
      curb = b;
    }
    acc += h[(size_t)n * HD + c];
  }
  atomicAdd(&sums[(size_t)curb * HD + c], acc);
}

__global__ __launch_bounds__(256) void k_cnt(const int* __restrict__ batch,
    float* __restrict__ cnt) {
  int n = blockIdx.x * 256 + threadIdx.x;
  if (n < NN) atomicAdd(&cnt[batch[n]], 1.f);
}

__global__ __launch_bounds__(256) void k_div(const float4* __restrict__ sums4,
    const float* __restrict__ cnt, float4* __restrict__ g4) {
  int idx = blockIdx.x * 256 + threadIdx.x;
  if (idx >= NB * 32) return;
  int b = idx >> 5;
  float inv = 1.f / fmaxf(cnt[b], 1.f);
  float4 v = sums4[idx];
  g4[idx] = make_float4(v.x * inv, v.y * inv, v.z * inv, v.w * inv);
}

// ---------------- row L2 normalize (in-place safe): one wave per row --------
__global__ __launch_bounds__(256) void k_norm(float* g) {
  int wave = threadIdx.x >> 6, lane = threadIdx.x & 63;
  int row = blockIdx.x * 4 + wave;
  if (row >= NB) return;
  float2 v = ((const float2*)(g + (size_t)row * HD))[lane];
  float sq = v.x * v.x + v.y * v.y;
#pragma unroll
  for (int o = 32; o > 0; o >>= 1) sq += __shfl_xor(sq, o, 64);
  float inv = 1.f / fmaxf(sqrtf(sq), 1e-12f);
  ((float2*)(g + (size_t)row * HD))[lane] = make_float2(v.x * inv, v.y * inv);
}

extern "C" void kernel_launch(void* const* d_in, const int* in_sizes, int n_in,
                              void* d_out, int out_size, void* d_ws, size_t ws_size,
                              hipStream_t stream) {
  // workspace (floats): round-9 layout + 1.31 MB packed split weights
  const size_t need = (size_t)NN * HD * 2 + (size_t)NB * PHD + (size_t)NB * HD
                      + NB + (size_t)SBLK * 256 + 256 + (size_t)NL * 2 * 16384;
  if (ws_size < need * sizeof(float)) {
    k_zero<<<(out_size + 255) / 256, 256, 0, stream>>>((float*)d_out, out_size);
    return;
  }

  const int* x = (const int*)d_in[0];
  const int* ei = (const int*)d_in[1];
  const int* batch = (const int*)d_in[2];
  const float* emb = (const float*)d_in[3];
  const float* eps = (const float*)d_in[4];
  const float* w1 = (const float*)d_in[5];
  const float* b1 = (const float*)d_in[6];
  const float* w2 = (const float*)d_in[7];
  const float* b2 = (const float*)d_in[8];
  const float* gamma = (const float*)d_in[9];
  const float* beta = (const float*)d_in[10];
  const float* pw1 = (const float*)d_in[11];
  const float* pb1 = (const float*)d_in[12];
  const float* pw2 = (const float*)d_in[13];
  const float* pb2 = (const float*)d_in[14];
  float* out = (float*)d_out;

  float* h = (float*)d_ws;                        // NN*HD
  float* A = h + (size_t)NN * HD;                 // NN*HD
  float* g1 = A + (size_t)NN * HD;                // NB*PHD (proj scratch, late)
  float* sums = g1 + (size_t)NB * PHD;            // NB*HD
  float* cnt = sums + (size_t)NB * HD;            // NB
  float* partial = cnt + NB;                      // SBLK*256
  float* stats = partial + (size_t)SBLK * 256;    // 256
  short* wpk = (short*)(stats + 256);             // NL*2*2*16384 shorts
  float* g = out;                                 // NB*HD in d_out

  // CSR arrays alias g1 (used only during layers; g1 only after pooling)
  int* rowptr = (int*)g1;                         // NN+1
  int* cur = rowptr + NN + 1;                     // NN
  int* blksum = cur + NN;                         // NBLK
  int* blkoff = blksum + 1024;                    // NBLK
  int* csr_src = blkoff + 1024;                   // NE

  const int* src = ei;
  const int* dst = ei + NE;

  // ---- build CSR by destination (once) ----
  k_zero_int<<<(NN + 255) / 256, 256, 0, stream>>>(cur, NN);
  k_hist<<<(NE + 255) / 256, 256, 0, stream>>>(dst, cur);
  k_scan1<<<NBLK, 256, 0, stream>>>(cur, rowptr, blksum);
  k_scan2<<<1, 256, 0, stream>>>(blksum, blkoff);
  k_scan3<<<NBLK, 256, 0, stream>>>(rowptr, blkoff);
  k_zero_int<<<(NN + 255) / 256, 256, 0, stream>>>(cur, NN);
  k_fill<<<(NE + 255) / 256, 256, 0, stream>>>(src, dst, rowptr, cur, csr_src);

  // ---- split & pack all layer weights for MFMA (once) ----
  k_convw<<<(NL * 2 * 16384 + 255) / 256, 256, 0, stream>>>(w1, w2, wpk);

  k_encoder<<<(NN * HD + 255) / 256, 256, 0, stream>>>(x, emb, h);

  for (int l = 0; l < NL; ++l) {
    k_agg<<<(NN * 64 + 255) / 256, 256, 0, stream>>>(h, rowptr, csr_src, eps, l, A);
    // in-place MFMA GEMMs: A = relu(A@w1+b1); A = A@w2+b2
    k_gemm_mfma<true><<<NN / 64, 256, 0, stream>>>(
        A, wpk + (size_t)(l * 2 + 0) * 32768, b1 + (size_t)l * HD, A);
    k_gemm_mfma<false><<<NN / 64, 256, 0, stream>>>(
        A, wpk + (size_t)(l * 2 + 1) * 32768, b2 + (size_t)l * HD, A);
    k_stats1<<<SBLK, 256, 0, stream>>>(A, partial);
    k_stats2<<<1, 256, 0, stream>>>(partial, stats);
    k_bn<<<(NN * 32 + 255) / 256, 256, 0, stream>>>(
        (const float4*)A, stats, gamma + (size_t)l * HD, beta + (size_t)l * HD,
        (float4*)h);
  }

  k_zero<<<(NB * HD + NB + 255) / 256, 256, 0, stream>>>(sums, NB * HD + NB);
  k_pool<<<NN / 64, 128, 0, stream>>>(h, batch, sums);
  k_cnt<<<(NN + 255) / 256, 256, 0, stream>>>(batch, cnt);
  k_div<<<(NB * 32 + 255) / 256, 256, 0, stream>>>(
      (const float4*)sums, cnt, (float4*)g);

  k_gemm<128, 512, 8, true><<<NB / 16, 256, 0, stream>>>(g, pw1, pb1, g1);
  k_gemm<512, 128, 2, false><<<NB / 16, 256, 0, stream>>>(g1, pw2, pb2, g);
  k_norm<<<(NB + 3) / 4, 256, 0, stream>>>(g);
}

// Round 15
// 1414.744 us; speedup vs baseline: 5.1977x; 1.2350x over previous
//
#include <hip/hip_runtime.h>

#define NN 200000     // nodes
#define NE 640000     // edges
#define HD 128        // hidden
#define NL 5          // layers
#define PHD 512       // proj hidden
#define NB 8000       // graphs
#define MAXV 119
#define SBLK 1024     // legacy sizing constant (workspace formula only)
#define NBLK 782      // ceil(NN/256) scan blocks
#define GBLK (NN / 64) // 3125 gemm blocks = stats partials

typedef short bf16x8 __attribute__((ext_vector_type(8)));
typedef float f32x4 __attribute__((ext_vector_type(4)));

// split fp32 -> bf16 hi (truncate) + bf16 lo (RNE of exact residual).
__device__ __forceinline__ void split_bf16(float f, short& hi, short& lo) {
  unsigned u = __float_as_uint(f);
  hi = (short)(u >> 16);
  float fh = __uint_as_float(u & 0xffff0000u);
  float fl = f - fh;
  unsigned ul = __float_as_uint(fl);
  lo = (short)((ul + 0x7fffu + ((ul >> 16) & 1u)) >> 16);
}

// ---------------- AtomEncoder ----------------
__global__ __launch_bounds__(256) void k_encoder(const int* __restrict__ x,
    const float* __restrict__ emb, float* __restrict__ h) {
  int idx = blockIdx.x * 256 + threadIdx.x;
  if (idx >= NN * HD) return;
  int n = idx >> 7, c = idx & 127;
  const int* xr = x + n * 9;
  float acc = 0.f;
#pragma unroll
  for (int s = 0; s < 9; ++s)
    acc += emb[(s * MAXV + xr[s]) * HD + c];
  h[idx] = acc;
}

// ================= CSR build ====
__global__ __launch_bounds__(256) void k_zero_int(int* __restrict__ p, int n) {
  int i = blockIdx.x * 256 + threadIdx.x;
  if (i < n) p[i] = 0;
}

__global__ __launch_bounds__(256) void k_hist(const int* __restrict__ dst,
    int* __restrict__ deg) {
  int e = blockIdx.x * 256 + threadIdx.x;
  if (e < NE) atomicAdd(&deg[dst[e]], 1);
}

__global__ __launch_bounds__(256) void k_scan1(const int* __restrict__ deg,
    int* __restrict__ rowptr, int* __restrict__ blksum) {
  int t = threadIdx.x;
  int i = blockIdx.x * 256 + t;
  int v = (i < NN) ? deg[i] : 0;
  __shared__ int s[256];
  s[t] = v;
  __syncthreads();
  for (int off = 1; off < 256; off <<= 1) {
    int x = (t >= off) ? s[t - off] : 0;
    __syncthreads();
    s[t] += x;
    __syncthreads();
  }
  if (i < NN) rowptr[i] = s[t] - v;
  if (t == 255) blksum[blockIdx.x] = s[255];
}

__global__ __launch_bounds__(256) void k_scan2(const int* __restrict__ blksum,
    int* __restrict__ blkoff) {
  int t = threadIdx.x;
  int base = t * 4;
  int v[4];
#pragma unroll
  for (int k = 0; k < 4; ++k) v[k] = (base + k < NBLK) ? blksum[base + k] : 0;
  int p1 = v[0], p2 = p1 + v[1], p3 = p2 + v[2], tot = p3 + v[3];
  __shared__ int s[256];
  s[t] = tot;
  __syncthreads();
  for (int off = 1; off < 256; off <<= 1) {
    int x = (t >= off) ? s[t - off] : 0;
    __syncthreads();
    s[t] += x;
    __syncthreads();
  }
  int excl = s[t] - tot;
  if (base + 0 < NBLK) blkoff[base + 0] = excl;
  if (base + 1 < NBLK) blkoff[base + 1] = excl + p1;
  if (base + 2 < NBLK) blkoff[base + 2] = excl + p2;
  if (base + 3 < NBLK) blkoff[base + 3] = excl + p3;
}

__global__ __launch_bounds__(256) void k_scan3(int* __restrict__ rowptr,
    const int* __restrict__ blkoff) {
  int i = blockIdx.x * 256 + threadIdx.x;
  if (i < NN) rowptr[i] += blkoff[blockIdx.x];
  if (i == 0) rowptr[NN] = NE;
}

__global__ __launch_bounds__(256) void k_fill(const int* __restrict__ src,
    const int* __restrict__ dst, const int* __restrict__ rowptr,
    int* __restrict__ cur, int* __restrict__ csr_src) {
  int e = blockIdx.x * 256 + threadIdx.x;
  if (e >= NE) return;
  int d = dst[e];
  int pos = rowptr[d] + atomicAdd(&cur[d], 1);
  csr_src[pos] = src[e];
}

// ======== GIN aggregate, layer 0 (no BN on input) ========
__global__ __launch_bounds__(256) void k_agg(const float* __restrict__ h,
    const int* __restrict__ rowptr, const int* __restrict__ csr_src,
    const float* __restrict__ eps, int l, float* __restrict__ A) {
  int gid = blockIdx.x * 256 + threadIdx.x;
  int node = gid >> 6, lane = gid & 63;
  if (node >= NN) return;
  float e = 1.f + eps[l];
  float2 v = ((const float2*)(h + (size_t)node * HD))[lane];
  float2 acc = make_float2(e * v.x, e * v.y);
  int beg = rowptr[node], end = rowptr[node + 1];
  for (int t = beg; t < end; ++t) {
    int j = csr_src[t];
    float2 u = ((const float2*)(h + (size_t)j * HD))[lane];
    acc.x += u.x;
    acc.y += u.y;
  }
  ((float2*)(A + (size_t)node * HD))[lane] = acc;
}

// ======== GIN aggregate with fused BN+ReLU on the input Z ========
// h[j,c] = relu(Z[j,c]*a_c + b_c) computed on the fly from stats.
__global__ __launch_bounds__(256) void k_agg_bn(const float* __restrict__ Z,
    const int* __restrict__ rowptr, const int* __restrict__ csr_src,
    const float* __restrict__ eps, int l, const float* __restrict__ stats,
    const float* __restrict__ gamma, const float* __restrict__ beta,
    float* __restrict__ A) {
  int gid = blockIdx.x * 256 + threadIdx.x;
  int node = gid >> 6, lane = gid & 63;
  if (node >= NN) return;
  const float invn = 1.f / NN;
  int c0 = lane * 2;
  float mu0 = stats[c0] * invn, mu1 = stats[c0 + 1] * invn;
  float va0 = stats[128 + c0] * invn - mu0 * mu0;
  float va1 = stats[128 + c0 + 1] * invn - mu1 * mu1;
  float a0 = gamma[c0] * rsqrtf(va0 + 1e-5f);
  float a1 = gamma[c0 + 1] * rsqrtf(va1 + 1e-5f);
  float b0 = beta[c0] - mu0 * a0;
  float b1 = beta[c0 + 1] - mu1 * a1;
  float e = 1.f + eps[l];
  float2 z = ((const float2*)(Z + (size_t)node * HD))[lane];
  float2 acc;
  acc.x = e * fmaxf(z.x * a0 + b0, 0.f);
  acc.y = e * fmaxf(z.y * a1 + b1, 0.f);
  int beg = rowptr[node], end = rowptr[node + 1];
  for (int t = beg; t < end; ++t) {
    int j = csr_src[t];
    float2 u = ((const float2*)(Z + (size_t)j * HD))[lane];
    acc.x += fmaxf(u.x * a0 + b0, 0.f);
    acc.y += fmaxf(u.y * a1 + b1, 0.f);
  }
  ((float2*)(A + (size_t)node * HD))[lane] = acc;
}

// ==== pre-split & pack weights into MFMA fragment order ====
__global__ __launch_bounds__(256) void k_convw(const float* __restrict__ w1,
    const float* __restrict__ w2, short* __restrict__ wpk) {
  int idx = blockIdx.x * 256 + threadIdx.x;
  if (idx >= NL * 2 * 16384) return;
  int l = idx / (2 * 16384);
  int rem = idx % (2 * 16384);
  int mat = rem / 16384;
  int e = rem % 16384;
  int k = e >> 7, n = e & 127;
  float f = (mat ? w2 : w1)[(size_t)l * 16384 + e];
  short hi, lo;
  split_bf16(f, hi, lo);
  int kk = k >> 5, j = k & 7, kg = (k >> 3) & 3, nt = n >> 4, nc = n & 15;
  int lane = (kg << 4) | nc;
  size_t fo = (((size_t)kk * 8 + nt) * 64 + lane) * 8 + j;
  size_t base = (size_t)(l * 2 + mat) * 32768;
  wpk[base + fo] = hi;
  wpk[base + 16384 + fo] = lo;
}

// ==== node GEMM via MFMA bf16x3, optional fused column-stats epilogue ====
// Frag layout proven on HW (round 13). STATS: per-block col sum/sumsq ->
// partial[blk*256 + {0:128 sum,128:256 sumsq}].
template <bool RELU, bool STATS>
__global__ __launch_bounds__(256) void k_gemm_mfma(const float* A,
    const short* __restrict__ wpk_mat, const float* __restrict__ bias,
    float* out, float* __restrict__ partial) {
  const int lane = threadIdx.x & 63;
  const int wid = threadIdx.x >> 6;
  const size_t row0 = (size_t)blockIdx.x * 64 + wid * 16;
  const int mrow = lane & 15;
  const int kg = lane >> 4;
  const float* Arow = A + (row0 + mrow) * HD;
  const bf16x8* wb = (const bf16x8*)wpk_mat;

  f32x4 acc[8];
#pragma unroll
  for (int i = 0; i < 8; ++i) {
    acc[i][0] = 0.f; acc[i][1] = 0.f; acc[i][2] = 0.f; acc[i][3] = 0.f;
  }

#pragma unroll
  for (int kk = 0; kk < 4; ++kk) {
    const int kbase = kk * 32 + kg * 8;
    float4 a0 = *(const float4*)(Arow + kbase);
    float4 a1 = *(const float4*)(Arow + kbase + 4);
    float av[8] = {a0.x, a0.y, a0.z, a0.w, a1.x, a1.y, a1.z, a1.w};
    bf16x8 ahi, alo;
#pragma unroll
    for (int j = 0; j < 8; ++j) {
      short hi, lo;
      split_bf16(av[j], hi, lo);
      ahi[j] = hi;
      alo[j] = lo;
    }
#pragma unroll
    for (int nt = 0; nt < 8; ++nt) {
      int f = (kk * 8 + nt) * 64 + lane;
      bf16x8 whi = wb[f];
      bf16x8 wlo = wb[2048 + f];
      acc[nt] = __builtin_amdgcn_mfma_f32_16x16x32_bf16(alo, whi, acc[nt], 0, 0, 0);
      acc[nt] = __builtin_amdgcn_mfma_f32_16x16x32_bf16(ahi, wlo, acc[nt], 0, 0, 0);
      acc[nt] = __builtin_amdgcn_mfma_f32_16x16x32_bf16(ahi, whi, acc[nt], 0, 0, 0);
    }
  }

  const int m0 = kg * 4;
  const int nc = lane & 15;
  __shared__ float bs[4][128];
  __shared__ float bq[4][128];
  float sarr[8], qarr[8];
#pragma unroll
  for (int nt = 0; nt < 8; ++nt) {
    float bv = bias[nt * 16 + nc];
    float s = 0.f, q = 0.f;
#pragma unroll
    for (int r = 0; r < 4; ++r) {
      float v = acc[nt][r] + bv;
      if (RELU) v = fmaxf(v, 0.f);
      out[(row0 + m0 + r) * HD + nt * 16 + nc] = v;
      if (STATS) { s += v; q += v * v; }
    }
    if (STATS) { sarr[nt] = s; qarr[nt] = q; }
  }
  if (STATS) {
#pragma unroll
    for (int nt = 0; nt < 8; ++nt) {
      float s = sarr[nt], q = qarr[nt];
      s += __shfl_xor(s, 16); s += __shfl_xor(s, 32);
      q += __shfl_xor(q, 16); q += __shfl_xor(q, 32);
      if (lane < 16) {
        bs[wid][nt * 16 + lane] = s;
        bq[wid][nt * 16 + lane] = q;
      }
    }
    __syncthreads();
    int t = threadIdx.x;
    if (t < 128)
      partial[(size_t)blockIdx.x * 256 + t] =
          bs[0][t] + bs[1][t] + bs[2][t] + bs[3][t];
    else
      partial[(size_t)blockIdx.x * 256 + t] =
          bq[0][t - 128] + bq[1][t - 128] + bq[2][t - 128] + bq[3][t - 128];
  }
}

// ---- reduce GBLK block-partials -> stats[256]; one block per stat column ----
__global__ __launch_bounds__(256) void k_stats2b(const float* __restrict__ partial,
    float* __restrict__ stats) {
  int col = blockIdx.x;
  float acc = 0.f;
  for (int b = threadIdx.x; b < GBLK; b += 256)
    acc += partial[(size_t)b * 256 + col];
  __shared__ float s[256];
  s[threadIdx.x] = acc;
  __syncthreads();
  for (int off = 128; off > 0; off >>= 1) {
    if (threadIdx.x < off) s[threadIdx.x] += s[threadIdx.x + off];
    __syncthreads();
  }
  if (threadIdx.x == 0) stats[col] = s[0];
}

// ---------------- generic fp32 GEMM (projection head) ----------------
template <int K, int COLS, int RPT, bool RELU>
__global__ __launch_bounds__(256) void k_gemm(const float* A,
    const float* __restrict__ W, const float* __restrict__ bias,
    float* out) {
  constexpr int CG = COLS / 4;
  constexpr int RG = 256 / CG;
  constexpr int TM = RG * RPT;
  __shared__ float As[TM * K];
  const int row0 = blockIdx.x * TM;
  const float4* A4 = (const float4*)(A + (size_t)row0 * K);
  float4* As4 = (float4*)As;
  for (int i = threadIdx.x; i < TM * K / 4; i += 256) As4[i] = A4[i];
  __syncthreads();
  const int cg = threadIdx.x % CG;
  const int rg = threadIdx.x / CG;
  const int r0 = rg * RPT;
  float acc[RPT][4] = {};
  const float4* W4 = (const float4*)W;
#pragma unroll 4
  for (int k = 0; k < K; k += 4) {
    float4 w0 = W4[(size_t)(k + 0) * CG + cg];
    float4 w1 = W4[(size_t)(k + 1) * CG + cg];
    float4 w2 = W4[(size_t)(k + 2) * CG + cg];
    float4 w3 = W4[(size_t)(k + 3) * CG + cg];
#pragma unroll
    for (int r = 0; r < RPT; ++r) {
      float4 a = As4[((r0 + r) * K + k) >> 2];
      acc[r][0] += a.x * w0.x + a.y * w1.x + a.z * w2.x + a.w * w3.x;
      acc[r][1] += a.x * w0.y + a.y * w1.y + a.z * w2.y + a.w * w3.y;
      acc[r][2] += a.x * w0.z + a.y * w1.z + a.z * w2.z + a.w * w3.z;
      acc[r][3] += a.x * w0.w + a.y * w1.w + a.z * w2.w + a.w * w3.w;
    }
  }
  float4 bv = ((const float4*)bias)[cg];
#pragma unroll
  for (int r = 0; r < RPT; ++r) {
    float4 o;
    o.x = acc[r][0] + bv.x;
    o.y = acc[r][1] + bv.y;
    o.z = acc[r][2] + bv.z;
    o.w = acc[r][3] + bv.w;
    if (RELU) {
      o.x = fmaxf(o.x, 0.f); o.y = fmaxf(o.y, 0.f);
      o.z = fmaxf(o.z, 0.f); o.w = fmaxf(o.w, 0.f);
    }
    ((float4*)(out + (size_t)(row0 + r0 + r) * COLS))[cg] = o;
  }
}

// ---------------- zero helper ----------------
__global__ __launch_bounds__(256) void k_zero(float* __restrict__ p, int n) {
  int i = blockIdx.x * 256 + threadIdx.x;
  if (i < n) p[i] = 0.f;
}

// ---------------- pooling with fused BN+ReLU on input Z ----------------
__global__ __launch_bounds__(128) void k_pool_bn(const float* __restrict__ Z,
    const float* __restrict__ stats, const float* __restrict__ gamma,
    const float* __restrict__ beta, const int* __restrict__ batch,
    float* __restrict__ sums) {
  int c = threadIdx.x;
  const float invn = 1.f / NN;
  float mu = stats[c] * invn;
  float va = stats[128 + c] * invn - mu * mu;
  float a = gamma[c] * rsqrtf(va + 1e-5f);
  float b = beta[c] - mu * a;
  int n0 = blockIdx.x * 64;
  int nend = n0 + 64;
  if (nend > NN) nend = NN;
  int curb = batch[n0];
  float acc = 0.f;
  for (int n = n0; n < nend; ++n) {
    int bb = batch[n];
    if (bb != curb) {
      atomicAdd(&sums[(size_t)curb * HD + c], acc);
      acc = 0.f;
      curb = bb;
    }
    acc += fmaxf(Z[(size_t)n * HD + c] * a + b, 0.f);
  }
  atomicAdd(&sums[(size_t)curb * HD + c], acc);
}

__global__ __launch_bounds__(256) void k_cnt(const int* __restrict__ batch,
    float* __restrict__ cnt) {
  int n = blockIdx.x * 256 + threadIdx.x;
  if (n < NN) atomicAdd(&cnt[batch[n]], 1.f);
}

__global__ __launch_bounds__(256) void k_div(const float4* __restrict__ sums4,
    const float* __restrict__ cnt, float4* __restrict__ g4) {
  int idx = blockIdx.x * 256 + threadIdx.x;
  if (idx >= NB * 32) return;
  int b = idx >> 5;
  float inv = 1.f / fmaxf(cnt[b], 1.f);
  float4 v = sums4[idx];
  g4[idx] = make_float4(v.x * inv, v.y * inv, v.z * inv, v.w * inv);
}

// ---------------- row L2 normalize ----------------
__global__ __launch_bounds__(256) void k_norm(float* g) {
  int wave = threadIdx.x >> 6, lane = threadIdx.x & 63;
  int row = blockIdx.x * 4 + wave;
  if (row >= NB) return;
  float2 v = ((const float2*)(g + (size_t)row * HD))[lane];
  float sq = v.x * v.x + v.y * v.y;
#pragma unroll
  for (int o = 32; o > 0; o >>= 1) sq += __shfl_xor(sq, o, 64);
  float inv = 1.f / fmaxf(sqrtf(sq), 1e-12f);
  ((float2*)(g + (size_t)row * HD))[lane] = make_float2(v.x * inv, v.y * inv);
}

extern "C" void kernel_launch(void* const* d_in, const int* in_sizes, int n_in,
                              void* d_out, int out_size, void* d_ws, size_t ws_size,
                              hipStream_t stream) {
  // workspace formula IDENTICAL to round-13 (which passed on this harness)
  const size_t need = (size_t)NN * HD * 2 + (size_t)NB * PHD + (size_t)NB * HD
                      + NB + (size_t)SBLK * 256 + 256 + (size_t)NL * 2 * 16384;
  if (ws_size < need * sizeof(float)) {
    k_zero<<<(out_size + 255) / 256, 256, 0, stream>>>((float*)d_out, out_size);
    return;
  }

  const int* x = (const int*)d_in[0];
  const int* ei = (const int*)d_in[1];
  const int* batch = (const int*)d_in[2];
  const float* emb = (const float*)d_in[3];
  const float* eps = (const float*)d_in[4];
  const float* w1 = (const float*)d_in[5];
  const float* b1 = (const float*)d_in[6];
  const float* w2 = (const float*)d_in[7];
  const float* b2 = (const float*)d_in[8];
  const float* gamma = (const float*)d_in[9];
  const float* beta = (const float*)d_in[10];
  const float* pw1 = (const float*)d_in[11];
  const float* pb1 = (const float*)d_in[12];
  const float* pw2 = (const float*)d_in[13];
  const float* pb2 = (const float*)d_in[14];
  float* out = (float*)d_out;

  float* h = (float*)d_ws;                        // NN*HD   (ping)
  float* A = h + (size_t)NN * HD;                 // NN*HD   (pong)
  float* g1 = A + (size_t)NN * HD;                // NB*PHD (proj scratch, late)
  float* sums = g1 + (size_t)NB * PHD;            // NB*HD
  float* cnt = sums + (size_t)NB * HD;            // NB
  float* legacy = cnt + NB;                       // SBLK*256 (reserved)
  float* stats = legacy + (size_t)SBLK * 256;     // 256
  short* wpk = (short*)(stats + 256);             // NL*2*2*16384 shorts
  float* g = out;

  // stats partials alias sums+cnt region (disjoint lifetime: layers vs pooling)
  float* partial = sums;                          // GBLK*256 = 800k <= 1.032M

  // CSR arrays alias g1 (layers-only lifetime)
  int* rowptr = (int*)g1;
  int* cur = rowptr + NN + 1;
  int* blksum = cur + NN;
  int* blkoff = blksum + 1024;
  int* csr_src = blkoff + 1024;

  const int* src = ei;
  const int* dst = ei + NE;

  // ---- build CSR by destination (once) ----
  k_zero_int<<<(NN + 255) / 256, 256, 0, stream>>>(cur, NN);
  k_hist<<<(NE + 255) / 256, 256, 0, stream>>>(dst, cur);
  k_scan1<<<NBLK, 256, 0, stream>>>(cur, rowptr, blksum);
  k_scan2<<<1, 256, 0, stream>>>(blksum, blkoff);
  k_scan3<<<NBLK, 256, 0, stream>>>(rowptr, blkoff);
  k_zero_int<<<(NN + 255) / 256, 256, 0, stream>>>(cur, NN);
  k_fill<<<(NE + 255) / 256, 256, 0, stream>>>(src, dst, rowptr, cur, csr_src);

  // ---- split & pack all layer weights for MFMA (once) ----
  k_convw<<<(NL * 2 * 16384 + 255) / 256, 256, 0, stream>>>(w1, w2, wpk);

  k_encoder<<<(NN * HD + 255) / 256, 256, 0, stream>>>(x, emb, h);

  // ping-pong: P holds the previous Z (or encoder h for l=0), Q gets new Z
  float* P = h;
  float* Q = A;
  for (int l = 0; l < NL; ++l) {
    if (l == 0)
      k_agg<<<(NN * 64 + 255) / 256, 256, 0, stream>>>(
          P, rowptr, csr_src, eps, l, Q);
    else
      k_agg_bn<<<(NN * 64 + 255) / 256, 256, 0, stream>>>(
          P, rowptr, csr_src, eps, l, stats,
          gamma + (size_t)(l - 1) * HD, beta + (size_t)(l - 1) * HD, Q);
    k_gemm_mfma<true, false><<<GBLK, 256, 0, stream>>>(
        Q, wpk + (size_t)(l * 2 + 0) * 32768, b1 + (size_t)l * HD, Q, nullptr);
    k_gemm_mfma<false, true><<<GBLK, 256, 0, stream>>>(
        Q, wpk + (size_t)(l * 2 + 1) * 32768, b2 + (size_t)l * HD, Q, partial);
    k_stats2b<<<256, 256, 0, stream>>>(partial, stats);
    float* tmp = P; P = Q; Q = tmp;
  }
  // final Z is in P; stats holds layer-4 stats

  k_zero<<<(NB * HD + NB + 255) / 256, 256, 0, stream>>>(sums, NB * HD + NB);
  k_pool_bn<<<NN / 64, 128, 0, stream>>>(
      P, stats, gamma + (size_t)(NL - 1) * HD, beta + (size_t)(NL - 1) * HD,
      batch, sums);
  k_cnt<<<(NN + 255) / 256, 256, 0, stream>>>(batch, cnt);
  k_div<<<(NB * 32 + 255) / 256, 256, 0, stream>>>(
      (const float4*)sums, cnt, (float4*)g);

  k_gemm<128, 512, 8, true><<<NB / 16, 256, 0, stream>>>(g, pw1, pb1, g1);
  k_gemm<512, 128, 2, false><<<NB / 16, 256, 0, stream>>>(g1, pw2, pb2, g);
  k_norm<<<(NB + 3) / 4, 256, 0, stream>>>(g);
}